// Round 1
// baseline (1049.791 us; speedup 1.0000x reference)
//
#include <hip/hip_runtime.h>

#define NN 200000
#define DMM 500
#define BB 4096
#define MM (2*BB)          // 8192 message rows
#define KP 2016            // padded K (msgs 1501 + h 500 -> 2001 -> 2016)
#define NG 2048            // padded gate columns: [r,z merged 0..999 | gi_n 1000..1499 | gh_n 1500..1999 | pad]

typedef unsigned short u16;
typedef __bf16 bf16x8 __attribute__((ext_vector_type(8)));
typedef float  f32x4  __attribute__((ext_vector_type(4)));

__device__ __forceinline__ u16 f2b(float x) {
  union { float f; unsigned u; } c; c.f = x;
  unsigned u = c.u;
  u += 0x7fffu + ((u >> 16) & 1u);   // RNE
  return (u16)(u >> 16);
}

__device__ __forceinline__ void async16(const u16* g, u16* l) {
  __builtin_amdgcn_global_load_lds(
      (const __attribute__((address_space(1))) void*)g,
      (__attribute__((address_space(3))) void*)l, 16, 0, 0);
}

// ---------------- copies ----------------
__global__ void copy_f4(const float4* __restrict__ in, float4* __restrict__ out, int n) {
  int i = blockIdx.x * blockDim.x + threadIdx.x;
  if (i < n) out[i] = in[i];
}
__global__ void copy_f1(const float* __restrict__ in, float* __restrict__ out, int n) {
  int i = blockIdx.x * blockDim.x + threadIdx.x;
  if (i < n) out[i] = in[i];
}

// ---------------- last-position per node ----------------
__global__ void lastpos_k(const int* __restrict__ src, const int* __restrict__ dst,
                          int* __restrict__ last_pos) {
  int m = blockIdx.x * blockDim.x + threadIdx.x;   // 0..MM-1
  int node = (m < BB) ? src[m] : dst[m - BB];
  atomicMax(&last_pos[node], m + 1);
}

// ---------------- weight prep ----------------
// Wc[n][k], n<1000: W_ih[n][k<1501], W_hh[n][k-1501] (r,z merged)
//           1000<=n<1500: gi_n -> W_ih[n][k<1501] only
//           1500<=n<2000: gh_n -> W_hh[n-500][k-1501] only
__global__ void prep_Wc(const float* __restrict__ W_ih, const float* __restrict__ W_hh,
                        const float* __restrict__ b_ih, const float* __restrict__ b_hh,
                        u16* __restrict__ Wc, float* __restrict__ bias_sum) {
  int n = blockIdx.x;                 // 0..NG-1
  u16* r = Wc + (size_t)n * KP;
  for (int k = threadIdx.x; k < KP; k += 256) {
    float v = 0.f;
    if (n < 1000) {
      if (k < 1501) v = W_ih[(size_t)n * 1501 + k];
      else if (k < 2001) v = W_hh[(size_t)n * 500 + (k - 1501)];
    } else if (n < 1500) {
      if (k < 1501) v = W_ih[(size_t)n * 1501 + k];
    } else if (n < 2000) {
      if (k >= 1501 && k < 2001) v = W_hh[(size_t)(n - 500) * 500 + (k - 1501)];
    }
    r[k] = f2b(v);
  }
  if (threadIdx.x == 0) {
    float b = 0.f;
    if (n < 1000) b = b_ih[n] + b_hh[n];
    else if (n < 1500) b = b_ih[n];
    else if (n < 2000) b = b_hh[n - 500];
    bias_sum[n] = b;
  }
}

// W1t[n][k] = W1[k][n] (W1 is [2000][80] row-major), zero-padded to [128][KP]
__global__ void prep_W1t(const float* __restrict__ W1, const float* __restrict__ b1,
                         u16* __restrict__ W1t, float* __restrict__ bias1) {
  int n = blockIdx.x;                 // 0..127
  u16* r = W1t + (size_t)n * KP;
  for (int k = threadIdx.x; k < KP; k += 256) {
    float v = 0.f;
    if (n < 80 && k < 2000) v = W1[(size_t)k * 80 + n];
    r[k] = f2b(v);
  }
  if (threadIdx.x == 0) bias1[n] = (n < 80) ? b1[n] : 0.f;
}

// ---------------- A-matrix prep (bf16 gathers) ----------------
// A1 row m: [mem[nodeA](500) | mem[nodeB](500) | ef(1) | cos((t-lu[nodeA])*tw+tb)(500) | mem[nodeA](500) | 0pad]
//   m<B: nodeA=src, nodeB=dst ; m>=B: nodeA=dst, nodeB=src
// A2 row m: [mem[s](500) | ce[s](500) | mem[x](500) | ce[x](500) | 0pad], x = dst (m<B) or neg (m>=B)
__global__ void prep_A(const float* __restrict__ mem, const float* __restrict__ ce,
                       const float* __restrict__ lu, const float* __restrict__ ef_tab,
                       const float* __restrict__ et, const float* __restrict__ tw,
                       const float* __restrict__ tb,
                       const int* __restrict__ src, const int* __restrict__ dst,
                       const int* __restrict__ neg, const int* __restrict__ eidx,
                       u16* __restrict__ A1, u16* __restrict__ A2) {
  int m = blockIdx.x;
  int t = threadIdx.x;
  bool second = m >= BB;
  int i = second ? m - BB : m;
  int s = src[i], d = dst[i], ng = neg[i];
  float tm = et[i];
  int nodeA = second ? d : s;
  int nodeB = second ? s : d;
  float efv = ef_tab[eidx[i]];
  float dt = tm - lu[nodeA];

  u16* r1 = A1 + (size_t)m * KP;
  for (int k = t; k < KP; k += 256) {
    float v;
    if (k < 500)        v = mem[(size_t)nodeA * DMM + k];
    else if (k < 1000)  v = mem[(size_t)nodeB * DMM + (k - 500)];
    else if (k == 1000) v = efv;
    else if (k < 1501)  { int j = k - 1001; v = cosf(dt * tw[j] + tb[j]); }
    else if (k < 2001)  v = mem[(size_t)nodeA * DMM + (k - 1501)];
    else                v = 0.f;
    r1[k] = f2b(v);
  }

  int other = second ? ng : d;
  u16* r2 = A2 + (size_t)m * KP;
  for (int k = t; k < KP; k += 256) {
    float v;
    if (k < 500)       v = mem[(size_t)s * DMM + k];
    else if (k < 1000) v = ce[(size_t)s * DMM + (k - 500)];
    else if (k < 1500) v = mem[(size_t)other * DMM + (k - 1000)];
    else if (k < 2000) v = ce[(size_t)other * DMM + (k - 1500)];
    else               v = 0.f;
    r2[k] = f2b(v);
  }
}

// ---------------- fused GEMM: C = A @ Bt^T (+bias, opt relu) ----------------
// bid < 1024 : gates[8192x2048] = A1 @ Wc^T     (64 M-tiles x 16 N-tiles)
// bid >= 1024: h1[8192x128]     = relu(A2 @ W1t^T + b1)   (64 M-tiles x 1 N-tile)
__global__ __launch_bounds__(256) void gemm_all(
    const u16* __restrict__ A1, const u16* __restrict__ A2,
    const u16* __restrict__ Wc, const u16* __restrict__ W1t,
    float* __restrict__ gates, float* __restrict__ h1,
    const float* __restrict__ bias_sum, const float* __restrict__ bias1) {
  __shared__ __align__(16) u16 As[128 * 32];
  __shared__ __align__(16) u16 Bs[128 * 32];

  int bid = blockIdx.x;
  const u16 *A, *Bt; float *C; const float *bias; int relu, cstride, bm, bn;
  if (bid < 1024) { A = A1; Bt = Wc;  C = gates; bias = bias_sum; relu = 0; cstride = NG;  bm = bid >> 4;   bn = bid & 15; }
  else            { A = A2; Bt = W1t; C = h1;    bias = bias1;    relu = 1; cstride = 128; bm = bid - 1024; bn = 0; }

  const int tid  = threadIdx.x;
  const int wave = tid >> 6, lane = tid & 63;
  const int wr = (wave >> 1) << 6;   // 0 / 64
  const int wc = (wave & 1) << 6;
  const size_t blockM = (size_t)bm * 128;
  const int    blockN = bn * 128;

  // staging: 8 chunks of 1KB per tile; wave w stages chunks 2w, 2w+1 of A and of B.
  const int rr = wave * 32 + (lane >> 2);        // tile-row for chunk 2w (+16 for 2w+1)
  const int cE = (lane & 3) * 8;                 // k-element offset within 32
  const u16* ga0 = A  + (blockM + rr) * KP + cE;
  const u16* ga1 = A  + (blockM + rr + 16) * KP + cE;
  const u16* gb0 = Bt + (size_t)(blockN + rr) * KP + cE;
  const u16* gb1 = Bt + (size_t)(blockN + rr + 16) * KP + cE;
  u16* la0 = As + wave * 1024;  u16* la1 = la0 + 512;
  u16* lb0 = Bs + wave * 1024;  u16* lb1 = lb0 + 512;

  f32x4 acc[4][4] = {};
  const int fr = lane & 15;
  const int fq = lane >> 4;

  for (int k0 = 0; k0 < KP; k0 += 32) {
    async16(ga0 + k0, la0);
    async16(ga1 + k0, la1);
    async16(gb0 + k0, lb0);
    async16(gb1 + k0, lb1);
    __syncthreads();               // drains vmcnt -> LDS tiles ready
    bf16x8 af[4], bfv[4];
#pragma unroll
    for (int mt = 0; mt < 4; mt++)
      af[mt] = *(const bf16x8*)(As + (wr + mt * 16 + fr) * 32 + fq * 8);
#pragma unroll
    for (int nt = 0; nt < 4; nt++)
      bfv[nt] = *(const bf16x8*)(Bs + (wc + nt * 16 + fr) * 32 + fq * 8);
#pragma unroll
    for (int mt = 0; mt < 4; mt++)
#pragma unroll
      for (int nt = 0; nt < 4; nt++)
        acc[mt][nt] = __builtin_amdgcn_mfma_f32_16x16x32_bf16(af[mt], bfv[nt], acc[mt][nt], 0, 0, 0);
    __syncthreads();               // LDS reuse guard
  }

  // epilogue: C/D layout col=lane&15, row=(lane>>4)*4+i
#pragma unroll
  for (int mt = 0; mt < 4; mt++) {
#pragma unroll
    for (int nt = 0; nt < 4; nt++) {
      int n_g = blockN + wc + nt * 16 + fr;
      float bv = bias[n_g];
#pragma unroll
      for (int i = 0; i < 4; i++) {
        size_t m_g = blockM + wr + mt * 16 + fq * 4 + i;
        float v = acc[mt][nt][i] + bv;
        if (relu) v = fmaxf(v, 0.f);
        C[m_g * cstride + n_g] = v;
      }
    }
  }
}

// ---------------- GRU elementwise (in-place: h_new into gates[m][0..499]) ----------------
__global__ void gru_k(const float* __restrict__ mem, const int* __restrict__ src,
                      const int* __restrict__ dst, float* __restrict__ gates) {
  int m = blockIdx.x;
  int node = (m < BB) ? src[m] : dst[m - BB];
  float* g = gates + (size_t)m * NG;
  const float* h = mem + (size_t)node * DMM;
  for (int j = threadIdx.x; j < DMM; j += 256) {
    float r  = 1.f / (1.f + expf(-g[j]));
    float z  = 1.f / (1.f + expf(-g[500 + j]));
    float nn = tanhf(g[1000 + j] + r * g[1500 + j]);
    g[j] = (1.f - z) * nn + z * h[j];     // each col<500 read+written only by its owner thread
  }
}

// ---------------- MLP tail: h2 = relu(h1@W2+b2); score = h2@W3+b3 ----------------
__global__ void scores_k(const float* __restrict__ h1, const float* __restrict__ W2,
                         const float* __restrict__ b2, const float* __restrict__ W3,
                         const float* __restrict__ b3, float* __restrict__ out) {
  __shared__ float sW2[800], sb2[10], sW3[10], sb3;
  int t = threadIdx.x;
  for (int i = t; i < 800; i += 256) sW2[i] = W2[i];
  if (t < 10) { sb2[t] = b2[t]; sW3[t] = W3[t]; }
  if (t == 0) sb3 = b3[0];
  __syncthreads();
  int m = blockIdx.x * 256 + t;           // 0..MM-1
  const float* h = h1 + (size_t)m * 128;
  float a[10];
#pragma unroll
  for (int o = 0; o < 10; o++) a[o] = sb2[o];
  for (int j = 0; j < 80; j++) {
    float hv = h[j];
#pragma unroll
    for (int o = 0; o < 10; o++) a[o] += hv * sW2[j * 10 + o];
  }
  float sc = sb3;
#pragma unroll
  for (int o = 0; o < 10; o++) sc += fmaxf(a[o], 0.f) * sW3[o];
  out[m] = sc;   // [score_pos(B) | score_neg(B)] == linear in m
}

// ---------------- scatter last message per node ----------------
__global__ void scatter_k(const int* __restrict__ src, const int* __restrict__ dst,
                          const int* __restrict__ last_pos, const float* __restrict__ gates,
                          const float* __restrict__ et, float* __restrict__ out_mem,
                          float* __restrict__ out_lu) {
  int m = blockIdx.x;
  int i = (m < BB) ? m : m - BB;
  int node = (m < BB) ? src[i] : dst[i];
  if (last_pos[node] != m + 1) return;
  const float* hn = gates + (size_t)m * NG;
  float* orow = out_mem + (size_t)node * DMM;
  for (int j = threadIdx.x; j < DMM; j += 256) orow[j] = hn[j];
  if (threadIdx.x == 0) out_lu[node] = et[i];
}

extern "C" void kernel_launch(void* const* d_in, const int* in_sizes, int n_in,
                              void* d_out, int out_size, void* d_ws, size_t ws_size,
                              hipStream_t stream) {
  const float* memory  = (const float*)d_in[0];
  const float* last_up = (const float*)d_in[1];
  const float* comm    = (const float*)d_in[2];
  const float* ef_tab  = (const float*)d_in[3];
  const float* etimes  = (const float*)d_in[4];
  const float* time_w  = (const float*)d_in[5];
  const float* time_b  = (const float*)d_in[6];
  const float* W_ih    = (const float*)d_in[7];
  const float* W_hh    = (const float*)d_in[8];
  const float* b_ih    = (const float*)d_in[9];
  const float* b_hh    = (const float*)d_in[10];
  const float* W1      = (const float*)d_in[11];
  const float* b1      = (const float*)d_in[12];
  const float* W2      = (const float*)d_in[13];
  const float* b2      = (const float*)d_in[14];
  const float* W3      = (const float*)d_in[15];
  const float* b3      = (const float*)d_in[16];
  const int* src       = (const int*)d_in[17];
  const int* dst       = (const int*)d_in[18];
  const int* neg       = (const int*)d_in[19];
  const int* eidx      = (const int*)d_in[20];
  (void)in_sizes; (void)n_in; (void)out_size; (void)ws_size;

  float* out        = (float*)d_out;
  float* out_scores = out;                         // 2*B
  float* out_mem    = out + 2 * BB;                // N*DM
  float* out_lu     = out_mem + (size_t)NN * DMM;  // N

  u16* A1        = (u16*)d_ws;                         // 8192*2016 bf16
  u16* A2        = A1 + (size_t)MM * KP;               // 8192*2016 bf16
  u16* Wc        = A2 + (size_t)MM * KP;               // 2048*2016 bf16
  u16* W1t       = Wc + (size_t)NG * KP;               // 128*2016 bf16
  float* bias_sum = (float*)(W1t + (size_t)128 * KP);  // 2048
  float* bias1    = bias_sum + NG;                     // 128
  float* gates    = bias1 + 128;                       // 8192*2048 f32
  float* h1       = gates + (size_t)MM * NG;           // 8192*128 f32
  int*   last_pos = (int*)(h1 + (size_t)MM * 128);     // N ints

  hipMemsetAsync(last_pos, 0, (size_t)NN * sizeof(int), stream);

  const int n4 = (NN * DMM) / 4;                       // 25,000,000 float4
  copy_f4<<<(n4 + 255) / 256, 256, 0, stream>>>((const float4*)memory, (float4*)out_mem, n4);
  copy_f1<<<(NN + 255) / 256, 256, 0, stream>>>(last_up, out_lu, NN);
  lastpos_k<<<MM / 256, 256, 0, stream>>>(src, dst, last_pos);
  prep_Wc<<<NG, 256, 0, stream>>>(W_ih, W_hh, b_ih, b_hh, Wc, bias_sum);
  prep_W1t<<<128, 256, 0, stream>>>(W1, b1, W1t, bias1);
  prep_A<<<MM, 256, 0, stream>>>(memory, comm, last_up, ef_tab, etimes, time_w, time_b,
                                 src, dst, neg, eidx, A1, A2);
  gemm_all<<<1088, 256, 0, stream>>>(A1, A2, Wc, W1t, gates, h1, bias_sum, bias1);
  gru_k<<<MM, 256, 0, stream>>>(memory, src, dst, gates);
  scores_k<<<MM / 256, 256, 0, stream>>>(h1, W2, b2, W3, b3, out_scores);
  scatter_k<<<MM, 256, 0, stream>>>(src, dst, last_pos, gates, etimes, out_mem, out_lu);
}